// Round 12
// baseline (433.680 us; speedup 1.0000x reference)
//
#include <hip/hip_runtime.h>
#include <hip/hip_fp16.h>

#define D 128
#define TPAD 136         // halves; GEMM LDS row stride
#define NPB 256          // nodes per bucket (dst >> 8)
#define KMAX 512         // max buckets (n <= 131072)
#define CHUNK 4096       // edges per block in bucket passes
#define SCAP 6144        // csr_build LDS edge cap (bucket avg 4092, sd ~64)
#define SRCMASK 0x1FFFF  // low 17 bits: src id (n <= 131072)

typedef _Float16 half_t;
typedef _Float16 f16x8 __attribute__((ext_vector_type(8)));
typedef float f32x4 __attribute__((ext_vector_type(4)));

// ---------------- setup: W packs + bucket histogram in ONE kernel ----------------

__global__ __launch_bounds__(256) void setup_kernel(const float* __restrict__ W1,
                                                    const float* __restrict__ W2,
                                                    const float* __restrict__ W3,
                                                    half_t* __restrict__ Wf1,
                                                    half_t* __restrict__ Wf2,
                                                    half_t* __restrict__ Wf3,
                                                    const int* __restrict__ dst,
                                                    int* __restrict__ bucket_cnt, int E) {
    __shared__ int scnt[KMAX];
    int b = blockIdx.x, t = threadIdx.x;
    if (b < 96) {
        const float* W = (b < 32) ? W1 : (b < 64) ? W2 : W3;
        half_t* Wf = (b < 32) ? Wf1 : (b < 64) ? Wf2 : Wf3;
        int bb = b & 31;                 // 0..31 = (s, tq)
        int s = bb >> 3, tq = bb & 7;
        for (int e = t; e < 512; e += 256) {
            int l = e >> 3, j = e & 7;
            int k = s * 32 + ((l >> 4) & 3) * 4 + (j & 3) + ((j >> 2) << 4);
            int nn = tq * 16 + (l & 15);
            Wf[(size_t)((s * 8 + tq) * 64 + l) * 8 + j] = (half_t)W[k * 128 + nn];
        }
    } else if (b >= 98) {
        for (int i = t; i < KMAX; i += 256) scnt[i] = 0;
        __syncthreads();
        int base = (b - 98) * CHUNK;
        int nE = min(CHUNK, E - base);
        for (int i = t; i < nE; i += 256)
            atomicAdd(&scnt[dst[base + i] >> 8], 1);
        __syncthreads();
        for (int i = t; i < KMAX; i += 256)
            if (scnt[i]) atomicAdd(&bucket_cnt[i], scnt[i]);
    }
}

// Exclusive scan of bucket_cnt[K] -> bucket_ptr[K+1], bucket_cur[K]=bucket_ptr[K]
__global__ __launch_bounds__(KMAX) void bucket_scan_kernel(const int* __restrict__ bucket_cnt,
                                                           int* __restrict__ bucket_ptr,
                                                           int* __restrict__ bucket_cur,
                                                           int K, int E) {
    __shared__ int sh[KMAX];
    int t = threadIdx.x;
    int v = (t < K) ? bucket_cnt[t] : 0;
    sh[t] = v;
    __syncthreads();
    for (int off = 1; off < KMAX; off <<= 1) {
        int add = (t >= off) ? sh[t - off] : 0;
        __syncthreads();
        sh[t] += add;
        __syncthreads();
    }
    if (t < K) {
        int ex = sh[t] - v;
        bucket_ptr[t] = ex;
        bucket_cur[t] = ex;
    }
    if (t == 0) bucket_ptr[K] = E;
}

// ---------------- GEMM core (R16 N-split, register-preloaded W) ----------------
// SCALE: multiply rows by dis[] in epilogue (layers 2-3). Layer 1 stores raw G.

template <bool SCALE>
__device__ __forceinline__ void gemm_core(half_t* sA, int tid, int base,
                                          const half_t* __restrict__ Wf,
                                          const float* __restrict__ dis,
                                          half_t* __restrict__ C, int n) {
    int l = tid & 63, w = tid >> 6;
    int m = l & 15, g = l >> 4;
    const f16x8* WF = (const f16x8*)Wf;

    // preload this wave's 8 W fragments (cols 32w .. 32w+31)
    f16x8 wB[4][2];
#pragma unroll
    for (int s = 0; s < 4; ++s)
#pragma unroll
        for (int j = 0; j < 2; ++j)
            wB[s][j] = WF[(size_t)(s * 8 + 2 * w + j) * 64 + l];

    f32x4 acc[4][2];
#pragma unroll
    for (int rt = 0; rt < 4; ++rt)
#pragma unroll
        for (int j = 0; j < 2; ++j) acc[rt][j] = (f32x4){0.f, 0.f, 0.f, 0.f};

#pragma unroll
    for (int s = 0; s < 4; ++s) {        // K steps of 32
#pragma unroll
        for (int rt = 0; rt < 4; ++rt) { // row-tiles 0..3 (16 rows each)
            union { f16x8 v; float2 f2[2]; } af;
            int a_off = (rt * 16 + m) * TPAD + s * 32 + 4 * g;
            af.f2[0] = *(const float2*)&sA[a_off];        // k +0..3
            af.f2[1] = *(const float2*)&sA[a_off + 16];   // k +16..19
            acc[rt][0] = __builtin_amdgcn_mfma_f32_16x16x32_f16(af.v, wB[s][0], acc[rt][0], 0, 0, 0);
            acc[rt][1] = __builtin_amdgcn_mfma_f32_16x16x32_f16(af.v, wB[s][1], acc[rt][1], 0, 0, 0);
        }
    }

    float dd[4][4];
#pragma unroll
    for (int rt = 0; rt < 4; ++rt)
#pragma unroll
        for (int r = 0; r < 4; ++r) {
            int row = base + rt * 16 + 4 * g + r;
            dd[rt][r] = SCALE ? ((row < n) ? dis[row] : 0.f) : 1.f;
        }
    __syncthreads();            // all frag reads done before clobbering sA
#pragma unroll
    for (int rt = 0; rt < 4; ++rt)
#pragma unroll
        for (int j = 0; j < 2; ++j)
#pragma unroll
            for (int r = 0; r < 4; ++r)
                sA[(rt * 16 + 4 * g + r) * TPAD + (2 * w + j) * 16 + m] =
                    (half_t)(acc[rt][j][r] * dd[rt][r]);
    __syncthreads();
#pragma unroll
    for (int q = 0; q < 4; ++q) {
        int f4 = q * 256 + tid;         // 0..1023 ; 16 float4 per row, 64 rows
        int r = f4 >> 4, c = f4 & 15;
        int row = base + r;
        if (row < n)
            *(float4*)&C[(size_t)row * D + c * 8] = *(const float4*)&sA[r * TPAD + c * 8];
    }
}

// ---------------- R17: merged scatter + layer-1 GEMM (one dispatch, two roles) ----
// Blocks [0,gC): edge partition (bpack). Blocks [gC,gC+gM): G1 = fp16(x@W1),
// UNSCALED (no dis dependency) -> GEMM1 runs concurrently with the partition.
// LDS union: scatter 20 KB / gemm 17 KB.

__global__ __launch_bounds__(256) void scatter_gemm_kernel(const int* __restrict__ src,
                                                           const int* __restrict__ dst,
                                                           int* __restrict__ bucket_cur,
                                                           int* __restrict__ bpack, int E,
                                                           const float* __restrict__ A,
                                                           const half_t* __restrict__ Wf,
                                                           half_t* __restrict__ C, int n,
                                                           int gC) {
    __shared__ __align__(16) char smem[20480];
    int t = threadIdx.x;
    int b = blockIdx.x;

    if (b < gC) {               // ---- scatter role ----
        int* sdst = (int*)smem;                    // [CHUNK] 16 KB
        int* scnt = (int*)(smem + 16384);          // [KMAX]   2 KB
        int* sbase = (int*)(smem + 18432);         // [KMAX]   2 KB
        int base = b * CHUNK;
        int nE = min(CHUNK, E - base);
        for (int i = t; i < KMAX; i += 256) scnt[i] = 0;
        __syncthreads();
        for (int i = t; i < nE; i += 256) {
            int d = dst[base + i];
            sdst[i] = d;
            atomicAdd(&scnt[d >> 8], 1);
        }
        __syncthreads();
        for (int i = t; i < KMAX; i += 256) {
            int c = scnt[i];
            sbase[i] = c ? atomicAdd(&bucket_cur[i], c) : 0;
            scnt[i] = 0;                // reuse as local cursor
        }
        __syncthreads();
        for (int i = t; i < nE; i += 256) {
            int d = sdst[i];
            int bk = d >> 8;
            int pos = sbase[bk] + atomicAdd(&scnt[bk], 1);
            bpack[pos] = src[base + i] | ((d & 255) << 17);
        }
    } else {                    // ---- GEMM1 role (fp32 in, raw fp16 out) ----
        half_t* sA = (half_t*)smem;                // 64*TPAD halves, 17 KB
        int gbase = (b - gC) * 64;
        const float4* A4 = (const float4*)A;       // row stride = 32 float4
#pragma unroll
        for (int it = 0; it < 8; ++it) {
            int idx = it * 256 + t;                // 0..2047
            int r = idx >> 5, kq = idx & 31;
            int grow = gbase + r;
            float4 va = (grow < n) ? A4[(size_t)grow * 32 + kq]
                                   : make_float4(0.f, 0.f, 0.f, 0.f);
            union { half_t h[4]; float2 f2; } pk;
            pk.h[0] = (half_t)va.x; pk.h[1] = (half_t)va.y;
            pk.h[2] = (half_t)va.z; pk.h[3] = (half_t)va.w;
            *(float2*)&sA[r * TPAD + kq * 4] = pk.f2;
        }
        __syncthreads();
        gemm_core<false>(sA, t, gbase, Wf, nullptr, C, n);
    }
}

// Fused count+scan+fill on packed edges (LDS 26 KB).
__global__ __launch_bounds__(256) void csr_build_kernel(const int* __restrict__ bpack,
                                                        const int* __restrict__ bucket_ptr,
                                                        int* __restrict__ row_ptr,
                                                        float* __restrict__ dis,
                                                        int* __restrict__ csr_src,
                                                        int n, int E, int K) {
    __shared__ int scnt[NPB];
    __shared__ int sh[NPB];
    __shared__ int sedge[SCAP];     // 24 KB
    int b = blockIdx.x;
    int node0 = b << 8;
    int nn = min(NPB, n - node0);
    int t = threadIdx.x;
    int p0 = bucket_ptr[b], p1 = bucket_ptr[b + 1];
    int cnt = p1 - p0;
    bool stage = (cnt <= SCAP);     // wave-uniform
    scnt[t] = 0;
    __syncthreads();
    for (int i = t; i < cnt; i += 256) {
        int e = bpack[p0 + i];
        if (stage) sedge[i] = e;
        atomicAdd(&scnt[(e >> 17) & 255], 1);
    }
    __syncthreads();
    int v = scnt[t];
    sh[t] = v;
    __syncthreads();
    for (int off = 1; off < NPB; off <<= 1) {
        int add = (t >= off) ? sh[t - off] : 0;
        __syncthreads();
        sh[t] += add;
        __syncthreads();
    }
    int rowbase = p0 + sh[t] - v;   // exclusive
    if (t < nn) {
        row_ptr[node0 + t] = rowbase;
        dis[node0 + t] = rsqrtf((float)(v + 1)); // +1 self-loop
    }
    if (b == K - 1 && t == 0) row_ptr[n] = E;
    scnt[t] = rowbase;              // reuse as cursor
    __syncthreads();
    for (int i = t; i < cnt; i += 256) {
        int e = stage ? sedge[i] : bpack[p0 + i];
        int pos = atomicAdd(&scnt[(e >> 17) & 255], 1);
        csr_src[pos] = e & SRCMASK;
    }
}

// Layer 2/3 GEMMs: fp16 in, dis-scaled fp16 out (unchanged path).
__global__ __launch_bounds__(256) void gemm_mfma_f16in(const half_t* __restrict__ A,
                                                       const half_t* __restrict__ Wf,
                                                       const float* __restrict__ dis,
                                                       half_t* __restrict__ C, int n) {
    __shared__ half_t sA[64 * TPAD];
    int tid = threadIdx.x;
    int base = blockIdx.x * 64;

    const float4* A4 = (const float4*)A;     // fp16 row = 16 float4
#pragma unroll
    for (int it = 0; it < 4; ++it) {
        int idx = it * 256 + tid;            // 0..1023
        int r = idx >> 4, c16 = idx & 15;
        int grow = base + r;
        float4 va = (grow < n) ? A4[(size_t)grow * 16 + c16]
                               : make_float4(0.f, 0.f, 0.f, 0.f);
        *(float4*)&sA[r * TPAD + c16 * 8] = va;
    }
    __syncthreads();
    gemm_core<true>(sA, tid, base, Wf, dis, C, n);
}

// ---------------- Aggregation ----------------
// EDGESCALE (layer 1): input G is UNSCALED; per-edge term = dis[src]*G[src]
// (dis[src] is a wave-uniform broadcast load from the L2-resident dis array);
// self term = dis_i*G[i]. Otherwise (layers 2-3): input H' already dis-scaled.
// F16OUT: write relu'd fp16 (layers 1-2).

template <bool F16OUT, bool EDGESCALE>
__global__ __launch_bounds__(256) void aggregate_kernel(const __half2* __restrict__ Hs,
                                                        const int* __restrict__ row_ptr,
                                                        const int* __restrict__ csr_src,
                                                        const float* __restrict__ dis,
                                                        const float* __restrict__ b,
                                                        void* __restrict__ outv, int n) {
    int node = blockIdx.x * 4 + (threadIdx.x >> 6);
    if (node >= n) return;
    int lane = threadIdx.x & 63;

    float di = dis[node];
    float2 s0 = __half22float2(Hs[(size_t)node * 64 + lane]);
    float selfs = EDGESCALE ? di : 1.f;
    float accx = selfs * s0.x, accy = selfs * s0.y;     // self-loop term

    int p0 = row_ptr[node], p1 = row_ptr[node + 1];
    int p = p0;
    int nb8 = (p1 - p0) >> 3;
    if (nb8 > 0) {
        int idx[8];
#pragma unroll
        for (int u = 0; u < 8; ++u) idx[u] = csr_src[p + u];
        for (int bb = 1; bb < nb8; ++bb) {
            int nxt[8];
#pragma unroll
            for (int u = 0; u < 8; ++u) nxt[u] = csr_src[p + 8 + u];   // prefetch
            __half2 v[8];
            float sc[8];
#pragma unroll
            for (int u = 0; u < 8; ++u) {
                v[u] = Hs[(size_t)idx[u] * 64 + lane];
                sc[u] = EDGESCALE ? dis[idx[u]] : 1.f;   // broadcast load
            }
#pragma unroll
            for (int u = 0; u < 8; ++u) {
                float2 f = __half22float2(v[u]);
                if (EDGESCALE) { accx = fmaf(sc[u], f.x, accx); accy = fmaf(sc[u], f.y, accy); }
                else           { accx += f.x; accy += f.y; }
            }
#pragma unroll
            for (int u = 0; u < 8; ++u) idx[u] = nxt[u];
            p += 8;
        }
        {
            __half2 v[8];
            float sc[8];
#pragma unroll
            for (int u = 0; u < 8; ++u) {
                v[u] = Hs[(size_t)idx[u] * 64 + lane];
                sc[u] = EDGESCALE ? dis[idx[u]] : 1.f;
            }
#pragma unroll
            for (int u = 0; u < 8; ++u) {
                float2 f = __half22float2(v[u]);
                if (EDGESCALE) { accx = fmaf(sc[u], f.x, accx); accy = fmaf(sc[u], f.y, accy); }
                else           { accx += f.x; accy += f.y; }
            }
            p += 8;
        }
    }
    for (; p < p1; ++p) {
        int s = csr_src[p];
        float2 f = __half22float2(Hs[(size_t)s * 64 + lane]);
        float sc = EDGESCALE ? dis[s] : 1.f;
        if (EDGESCALE) { accx = fmaf(sc, f.x, accx); accy = fmaf(sc, f.y, accy); }
        else           { accx += f.x; accy += f.y; }
    }

    float2 bb2 = *(const float2*)(b + 2 * lane);
    float ox = fmaf(accx, di, bb2.x);
    float oy = fmaf(accy, di, bb2.y);
    if (F16OUT) {
        ox = fmaxf(ox, 0.f);                 // relu folded in (next GEMM input)
        oy = fmaxf(oy, 0.f);
        ((__half2*)outv)[(size_t)node * 64 + lane] = __floats2half2_rn(ox, oy);
    } else {
        float2 o; o.x = ox; o.y = oy;
        ((float2*)((float*)outv + (size_t)node * D))[lane] = o;
    }
}

// ---------------- launch ----------------

extern "C" void kernel_launch(void* const* d_in, const int* in_sizes, int n_in,
                              void* d_out, int out_size, void* d_ws, size_t ws_size,
                              hipStream_t stream) {
    const float* x  = (const float*)d_in[0];
    const int*   ei = (const int*)d_in[1];
    const float* W1 = (const float*)d_in[2];
    const float* b1 = (const float*)d_in[3];
    const float* W2 = (const float*)d_in[4];
    const float* b2 = (const float*)d_in[5];
    const float* W3 = (const float*)d_in[6];
    const float* b3 = (const float*)d_in[7];
    float* out = (float*)d_out;

    int n = in_sizes[0] / D;
    int E = in_sizes[1] / 2;
    const int* src = ei;
    const int* dst = ei + E;
    int K = (n + NPB - 1) >> 8;     // buckets

    char* ws = (char*)d_ws;
    half_t* hbuf     = (half_t*)ws; ws += (size_t)n * D * sizeof(half_t);  // H'/G fp16 (25.6 MB)
    half_t* outh     = (half_t*)ws; ws += (size_t)n * D * sizeof(half_t);  // relu'd out fp16 (25.6 MB)
    float* dis       = (float*)ws;  ws += (size_t)n * sizeof(float);
    int* row_ptr     = (int*)ws;    ws += (size_t)(n + 1) * sizeof(int);
    int* csr_src     = (int*)ws;    ws += (size_t)E * sizeof(int);
    int* bucket_cnt  = (int*)ws;    ws += KMAX * sizeof(int);
    int* bucket_ptr  = (int*)ws;    ws += (KMAX + 1) * sizeof(int);
    int* bucket_cur  = (int*)ws;    ws += KMAX * sizeof(int);
    ws = (char*)(((uintptr_t)ws + 15) & ~(uintptr_t)15);   // 16B align for W packs
    half_t* Wf1      = (half_t*)ws; ws += 128 * 128 * sizeof(half_t);
    half_t* Wf2      = (half_t*)ws; ws += 128 * 128 * sizeof(half_t);
    half_t* Wf3      = (half_t*)ws; ws += 128 * 128 * sizeof(half_t);
    // bpack aliases outh (NOT hbuf — GEMM1 writes hbuf concurrently with scatter).
    // Timeline: scatter_gemm writes bpack; csr_build reads it; agg1 then overwrites outh.
    int* bpack       = (int*)outh;

    int gC = (E + CHUNK - 1) / CHUNK; // 391
    int gM = (n + 63) / 64;           // 1563 (64-row blocks)
    int gA = (n + 3) / 4;             // 25000

    // 1) bucket_cnt = 0 (stream-ordered before setup's hist atomics)
    hipMemsetAsync(bucket_cnt, 0, KMAX * sizeof(int), stream);
    // 2) setup: W packs + dst histogram
    setup_kernel<<<98 + gC, 256, 0, stream>>>(W1, W2, W3, Wf1, Wf2, Wf3,
                                              dst, bucket_cnt, E);
    // 3) bucket scan
    bucket_scan_kernel<<<1, KMAX, 0, stream>>>(bucket_cnt, bucket_ptr, bucket_cur, K, E);
    // 4) MERGED: edge partition || GEMM1 (G1 = fp16(x@W1), unscaled)
    scatter_gemm_kernel<<<gC + gM, 256, 0, stream>>>(src, dst, bucket_cur, bpack, E,
                                                     x, Wf1, hbuf, n, gC);
    // 5) CSR build (packed edges) -> row_ptr, csr_src, dis
    csr_build_kernel<<<K, 256, 0, stream>>>(bpack, bucket_ptr, row_ptr, dis, csr_src, n, E, K);

    // Layer 1: out1 = relu(dis.(dis_src-weighted agg of G1) + b1) fp16
    aggregate_kernel<true, true><<<gA, 256, 0, stream>>>((const __half2*)hbuf, row_ptr, csr_src, dis, b1, outh, n);
    // Layer 2: H2 = fp16(dis*(out1@W2)) ; out2 = relu(agg+b2) fp16
    gemm_mfma_f16in<<<gM, 256, 0, stream>>>(outh, Wf2, dis, hbuf, n);
    aggregate_kernel<true, false><<<gA, 256, 0, stream>>>((const __half2*)hbuf, row_ptr, csr_src, dis, b2, outh, n);
    // Layer 3: H3 = fp16(dis*(out2@W3)) ; out = agg+b3 fp32
    gemm_mfma_f16in<<<gM, 256, 0, stream>>>(outh, Wf3, dis, hbuf, n);
    aggregate_kernel<false, false><<<gA, 256, 0, stream>>>((const __half2*)hbuf, row_ptr, csr_src, dis, b3, out, n);
}

// Round 13
// 404.446 us; speedup vs baseline: 1.0723x; 1.0723x over previous
//
#include <hip/hip_runtime.h>
#include <hip/hip_fp16.h>

#define D 128
#define TPAD 136         // halves; GEMM LDS row stride
#define NPB 256          // nodes per bucket (dst >> 8)
#define KMAX 512         // max buckets (n <= 131072)
#define CHUNK 4096       // edges per block in bucket passes
#define SRCMASK 0x1FFFF  // low 17 bits: src id (n <= 131072)

typedef _Float16 half_t;
typedef _Float16 f16x8 __attribute__((ext_vector_type(8)));
typedef float f32x4 __attribute__((ext_vector_type(4)));

// ---------------- setup: W packs + bucket histogram in ONE kernel ----------------

__global__ __launch_bounds__(256) void setup_kernel(const float* __restrict__ W1,
                                                    const float* __restrict__ W2,
                                                    const float* __restrict__ W3,
                                                    half_t* __restrict__ Wf1,
                                                    half_t* __restrict__ Wf2,
                                                    half_t* __restrict__ Wf3,
                                                    const int* __restrict__ dst,
                                                    int* __restrict__ bucket_cnt, int E) {
    __shared__ int scnt[KMAX];
    int b = blockIdx.x, t = threadIdx.x;
    if (b < 96) {
        const float* W = (b < 32) ? W1 : (b < 64) ? W2 : W3;
        half_t* Wf = (b < 32) ? Wf1 : (b < 64) ? Wf2 : Wf3;
        int bb = b & 31;                 // 0..31 = (s, tq)
        int s = bb >> 3, tq = bb & 7;
        for (int e = t; e < 512; e += 256) {
            int l = e >> 3, j = e & 7;
            int k = s * 32 + ((l >> 4) & 3) * 4 + (j & 3) + ((j >> 2) << 4);
            int nn = tq * 16 + (l & 15);
            Wf[(size_t)((s * 8 + tq) * 64 + l) * 8 + j] = (half_t)W[k * 128 + nn];
        }
    } else if (b >= 98) {
        for (int i = t; i < KMAX; i += 256) scnt[i] = 0;
        __syncthreads();
        int base = (b - 98) * CHUNK;
        int nE = min(CHUNK, E - base);
        for (int i = t; i < nE; i += 256)
            atomicAdd(&scnt[dst[base + i] >> 8], 1);
        __syncthreads();
        for (int i = t; i < KMAX; i += 256)
            if (scnt[i]) atomicAdd(&bucket_cnt[i], scnt[i]);
    }
}

// Exclusive scan of bucket_cnt[K] -> bucket_ptr[K+1], bucket_cur[K]=bucket_ptr[K]
__global__ __launch_bounds__(KMAX) void bucket_scan_kernel(const int* __restrict__ bucket_cnt,
                                                           int* __restrict__ bucket_ptr,
                                                           int* __restrict__ bucket_cur,
                                                           int K, int E) {
    __shared__ int sh[KMAX];
    int t = threadIdx.x;
    int v = (t < K) ? bucket_cnt[t] : 0;
    sh[t] = v;
    __syncthreads();
    for (int off = 1; off < KMAX; off <<= 1) {
        int add = (t >= off) ? sh[t - off] : 0;
        __syncthreads();
        sh[t] += add;
        __syncthreads();
    }
    if (t < K) {
        int ex = sh[t] - v;
        bucket_ptr[t] = ex;
        bucket_cur[t] = ex;
    }
    if (t == 0) bucket_ptr[K] = E;
}

// bpack: ONE int per edge: src | (dst&255)<<17 — halves partition traffic.
__global__ __launch_bounds__(256) void bucket_scatter_kernel(const int* __restrict__ src,
                                                             const int* __restrict__ dst,
                                                             int* __restrict__ bucket_cur,
                                                             int* __restrict__ bpack, int E) {
    __shared__ int sdst[CHUNK];     // 16 KB
    __shared__ int scnt[KMAX];      // 2 KB
    __shared__ int sbase[KMAX];     // 2 KB
    int t = threadIdx.x;
    int base = blockIdx.x * CHUNK;
    int nE = min(CHUNK, E - base);
    for (int i = t; i < KMAX; i += 256) scnt[i] = 0;
    __syncthreads();
    for (int i = t; i < nE; i += 256) {
        int d = dst[base + i];
        sdst[i] = d;
        atomicAdd(&scnt[d >> 8], 1);
    }
    __syncthreads();
    for (int i = t; i < KMAX; i += 256) {
        int c = scnt[i];
        sbase[i] = c ? atomicAdd(&bucket_cur[i], c) : 0;
        scnt[i] = 0;                // reuse as local cursor
    }
    __syncthreads();
    for (int i = t; i < nE; i += 256) {
        int d = sdst[i];
        int b = d >> 8;
        int pos = sbase[b] + atomicAdd(&scnt[b], 1);
        bpack[pos] = src[base + i] | ((d & 255) << 17);
    }
}

// R18: count+scan only (R11-proven shape, packed edges) -> row_ptr, dis.
// Fill is deferred so it can run concurrently with GEMM1.
__global__ __launch_bounds__(256) void csr_count_kernel(const int* __restrict__ bpack,
                                                        const int* __restrict__ bucket_ptr,
                                                        int* __restrict__ row_ptr,
                                                        float* __restrict__ dis,
                                                        int n, int E, int K) {
    __shared__ int scnt[NPB];
    __shared__ int sh[NPB];
    int b = blockIdx.x;
    int node0 = b << 8;
    int nn = min(NPB, n - node0);
    int t = threadIdx.x;
    scnt[t] = 0;
    __syncthreads();
    int p0 = bucket_ptr[b], p1 = bucket_ptr[b + 1];
    for (int i = p0 + t; i < p1; i += 256)
        atomicAdd(&scnt[(bpack[i] >> 17) & 255], 1);
    __syncthreads();
    int v = scnt[t];
    sh[t] = v;
    __syncthreads();
    for (int off = 1; off < NPB; off <<= 1) {
        int add = (t >= off) ? sh[t - off] : 0;
        __syncthreads();
        sh[t] += add;
        __syncthreads();
    }
    if (t < nn) {
        row_ptr[node0 + t] = p0 + sh[t] - v;     // exclusive
        dis[node0 + t] = rsqrtf((float)(v + 1)); // +1 self-loop
    }
    if (b == K - 1 && t == 0) row_ptr[n] = E;
}

// ---------------- GEMM core (R16 N-split, register-preloaded W) ----------------

template <bool SCALE>
__device__ __forceinline__ void gemm_core(half_t* sA, int tid, int base,
                                          const half_t* __restrict__ Wf,
                                          const float* __restrict__ dis,
                                          half_t* __restrict__ C, int n) {
    int l = tid & 63, w = tid >> 6;
    int m = l & 15, g = l >> 4;
    const f16x8* WF = (const f16x8*)Wf;

    // preload this wave's 8 W fragments (cols 32w .. 32w+31)
    f16x8 wB[4][2];
#pragma unroll
    for (int s = 0; s < 4; ++s)
#pragma unroll
        for (int j = 0; j < 2; ++j)
            wB[s][j] = WF[(size_t)(s * 8 + 2 * w + j) * 64 + l];

    f32x4 acc[4][2];
#pragma unroll
    for (int rt = 0; rt < 4; ++rt)
#pragma unroll
        for (int j = 0; j < 2; ++j) acc[rt][j] = (f32x4){0.f, 0.f, 0.f, 0.f};

#pragma unroll
    for (int s = 0; s < 4; ++s) {        // K steps of 32
#pragma unroll
        for (int rt = 0; rt < 4; ++rt) { // row-tiles 0..3 (16 rows each)
            union { f16x8 v; float2 f2[2]; } af;
            int a_off = (rt * 16 + m) * TPAD + s * 32 + 4 * g;
            af.f2[0] = *(const float2*)&sA[a_off];        // k +0..3
            af.f2[1] = *(const float2*)&sA[a_off + 16];   // k +16..19
            acc[rt][0] = __builtin_amdgcn_mfma_f32_16x16x32_f16(af.v, wB[s][0], acc[rt][0], 0, 0, 0);
            acc[rt][1] = __builtin_amdgcn_mfma_f32_16x16x32_f16(af.v, wB[s][1], acc[rt][1], 0, 0, 0);
        }
    }

    float dd[4][4];
#pragma unroll
    for (int rt = 0; rt < 4; ++rt)
#pragma unroll
        for (int r = 0; r < 4; ++r) {
            int row = base + rt * 16 + 4 * g + r;
            dd[rt][r] = SCALE ? ((row < n) ? dis[row] : 0.f) : 1.f;
        }
    __syncthreads();            // all frag reads done before clobbering sA
#pragma unroll
    for (int rt = 0; rt < 4; ++rt)
#pragma unroll
        for (int j = 0; j < 2; ++j)
#pragma unroll
            for (int r = 0; r < 4; ++r)
                sA[(rt * 16 + 4 * g + r) * TPAD + (2 * w + j) * 16 + m] =
                    (half_t)(acc[rt][j][r] * dd[rt][r]);
    __syncthreads();
#pragma unroll
    for (int q = 0; q < 4; ++q) {
        int f4 = q * 256 + tid;         // 0..1023 ; 16 float4 per row, 64 rows
        int r = f4 >> 4, c = f4 & 15;
        int row = base + r;
        if (row < n)
            *(float4*)&C[(size_t)row * D + c * 8] = *(const float4*)&sA[r * TPAD + c * 8];
    }
}

// ---------------- R18: merged CSR-fill + layer-1 GEMM (one dispatch, two roles) ----
// Blocks [0,K): fill csr_src (needs row_ptr only, ~1 KB LDS).
// Blocks [K,K+gM): H1 = fp16(dis*(x@W1)) — dis is ready (csr_count ran before).
// Fill (~15-18 us) hides under GEMM1 (~27 us). agg1 keeps the proven
// pre-scaled gather path (R17's edge-scaling cost +18 us — reverted).

__global__ __launch_bounds__(256) void fill_gemm_kernel(const int* __restrict__ bpack,
                                                        const int* __restrict__ bucket_ptr,
                                                        const int* __restrict__ row_ptr,
                                                        int* __restrict__ csr_src, int K,
                                                        const float* __restrict__ A,
                                                        const half_t* __restrict__ Wf,
                                                        const float* __restrict__ dis,
                                                        half_t* __restrict__ C, int n) {
    __shared__ __align__(16) char smem[64 * TPAD * sizeof(half_t)];   // 17 KB union
    int b = blockIdx.x, t = threadIdx.x;

    if (b < K) {                // ---- fill role ----
        int* cursor = (int*)smem;          // [NPB] 1 KB
        int node0 = b << 8;
        int nn = min(NPB, n - node0);
        if (t < nn) cursor[t] = row_ptr[node0 + t];
        __syncthreads();
        int p0 = bucket_ptr[b], p1 = bucket_ptr[b + 1];
        for (int i = p0 + t; i < p1; i += 256) {
            int e = bpack[i];
            int pos = atomicAdd(&cursor[(e >> 17) & 255], 1);
            csr_src[pos] = e & SRCMASK;
        }
    } else {                    // ---- GEMM1 role (fp32 in, dis-scaled fp16 out) ----
        half_t* sA = (half_t*)smem;
        int base = (b - K) * 64;
        const float4* A4 = (const float4*)A;   // row stride = 32 float4
#pragma unroll
        for (int it = 0; it < 8; ++it) {
            int idx = it * 256 + t;            // 0..2047
            int r = idx >> 5, kq = idx & 31;
            int grow = base + r;
            float4 va = (grow < n) ? A4[(size_t)grow * 32 + kq]
                                   : make_float4(0.f, 0.f, 0.f, 0.f);
            union { half_t h[4]; float2 f2; } pk;
            pk.h[0] = (half_t)va.x; pk.h[1] = (half_t)va.y;
            pk.h[2] = (half_t)va.z; pk.h[3] = (half_t)va.w;
            *(float2*)&sA[r * TPAD + kq * 4] = pk.f2;
        }
        __syncthreads();
        gemm_core<true>(sA, t, base, Wf, dis, C, n);
    }
}

// Layer 2/3 GEMMs: fp16 in, dis-scaled fp16 out.
__global__ __launch_bounds__(256) void gemm_mfma_f16in(const half_t* __restrict__ A,
                                                       const half_t* __restrict__ Wf,
                                                       const float* __restrict__ dis,
                                                       half_t* __restrict__ C, int n) {
    __shared__ half_t sA[64 * TPAD];
    int tid = threadIdx.x;
    int base = blockIdx.x * 64;

    const float4* A4 = (const float4*)A;     // fp16 row = 16 float4
#pragma unroll
    for (int it = 0; it < 4; ++it) {
        int idx = it * 256 + tid;            // 0..1023
        int r = idx >> 4, c16 = idx & 15;
        int grow = base + r;
        float4 va = (grow < n) ? A4[(size_t)grow * 16 + c16]
                               : make_float4(0.f, 0.f, 0.f, 0.f);
        *(float4*)&sA[r * TPAD + c16 * 8] = va;
    }
    __syncthreads();
    gemm_core<true>(sA, tid, base, Wf, dis, C, n);
}

// ---------------- Aggregation: out[i] = dis_i*(H'[i] + sum_e H'[src_e]) + b ----------
// R15-proven form (pre-scaled H', no per-edge dis loads). F16OUT: relu'd fp16.

template <bool F16OUT>
__global__ __launch_bounds__(256) void aggregate_kernel(const __half2* __restrict__ Hs,
                                                        const int* __restrict__ row_ptr,
                                                        const int* __restrict__ csr_src,
                                                        const float* __restrict__ dis,
                                                        const float* __restrict__ b,
                                                        void* __restrict__ outv, int n) {
    int node = blockIdx.x * 4 + (threadIdx.x >> 6);
    if (node >= n) return;
    int lane = threadIdx.x & 63;

    float2 s0 = __half22float2(Hs[(size_t)node * 64 + lane]);
    float accx = s0.x, accy = s0.y;                     // self-loop term H'[i]

    int p0 = row_ptr[node], p1 = row_ptr[node + 1];
    int p = p0;
    int nb8 = (p1 - p0) >> 3;
    if (nb8 > 0) {
        int idx[8];
#pragma unroll
        for (int u = 0; u < 8; ++u) idx[u] = csr_src[p + u];
        for (int bb = 1; bb < nb8; ++bb) {
            int nxt[8];
#pragma unroll
            for (int u = 0; u < 8; ++u) nxt[u] = csr_src[p + 8 + u];   // prefetch
            __half2 v[8];
#pragma unroll
            for (int u = 0; u < 8; ++u) v[u] = Hs[(size_t)idx[u] * 64 + lane];
#pragma unroll
            for (int u = 0; u < 8; ++u) {
                float2 f = __half22float2(v[u]);
                accx += f.x; accy += f.y;
            }
#pragma unroll
            for (int u = 0; u < 8; ++u) idx[u] = nxt[u];
            p += 8;
        }
        {
            __half2 v[8];
#pragma unroll
            for (int u = 0; u < 8; ++u) v[u] = Hs[(size_t)idx[u] * 64 + lane];
#pragma unroll
            for (int u = 0; u < 8; ++u) {
                float2 f = __half22float2(v[u]);
                accx += f.x; accy += f.y;
            }
            p += 8;
        }
    }
    for (; p + 4 <= p1; p += 4) {
        int s0i = csr_src[p + 0];
        int s1i = csr_src[p + 1];
        int s2i = csr_src[p + 2];
        int s3i = csr_src[p + 3];
        __half2 v0 = Hs[(size_t)s0i * 64 + lane];
        __half2 v1 = Hs[(size_t)s1i * 64 + lane];
        __half2 v2 = Hs[(size_t)s2i * 64 + lane];
        __half2 v3 = Hs[(size_t)s3i * 64 + lane];
        float2 f0 = __half22float2(v0), f1 = __half22float2(v1);
        float2 f2 = __half22float2(v2), f3 = __half22float2(v3);
        accx += f0.x; accy += f0.y;
        accx += f1.x; accy += f1.y;
        accx += f2.x; accy += f2.y;
        accx += f3.x; accy += f3.y;
    }
    for (; p < p1; ++p) {
        int s = csr_src[p];
        float2 f = __half22float2(Hs[(size_t)s * 64 + lane]);
        accx += f.x; accy += f.y;
    }

    float di = dis[node];
    float2 bb2 = *(const float2*)(b + 2 * lane);
    float ox = fmaf(accx, di, bb2.x);
    float oy = fmaf(accy, di, bb2.y);
    if (F16OUT) {
        ox = fmaxf(ox, 0.f);                 // relu folded in (next GEMM input)
        oy = fmaxf(oy, 0.f);
        ((__half2*)outv)[(size_t)node * 64 + lane] = __floats2half2_rn(ox, oy);
    } else {
        float2 o; o.x = ox; o.y = oy;
        ((float2*)((float*)outv + (size_t)node * D))[lane] = o;
    }
}

// ---------------- launch ----------------

extern "C" void kernel_launch(void* const* d_in, const int* in_sizes, int n_in,
                              void* d_out, int out_size, void* d_ws, size_t ws_size,
                              hipStream_t stream) {
    const float* x  = (const float*)d_in[0];
    const int*   ei = (const int*)d_in[1];
    const float* W1 = (const float*)d_in[2];
    const float* b1 = (const float*)d_in[3];
    const float* W2 = (const float*)d_in[4];
    const float* b2 = (const float*)d_in[5];
    const float* W3 = (const float*)d_in[6];
    const float* b3 = (const float*)d_in[7];
    float* out = (float*)d_out;

    int n = in_sizes[0] / D;
    int E = in_sizes[1] / 2;
    const int* src = ei;
    const int* dst = ei + E;
    int K = (n + NPB - 1) >> 8;     // buckets

    char* ws = (char*)d_ws;
    half_t* hbuf     = (half_t*)ws; ws += (size_t)n * D * sizeof(half_t);  // H' fp16 (25.6 MB)
    half_t* outh     = (half_t*)ws; ws += (size_t)n * D * sizeof(half_t);  // relu'd out fp16 (25.6 MB)
    float* dis       = (float*)ws;  ws += (size_t)n * sizeof(float);
    int* row_ptr     = (int*)ws;    ws += (size_t)(n + 1) * sizeof(int);
    int* csr_src     = (int*)ws;    ws += (size_t)E * sizeof(int);
    int* bucket_cnt  = (int*)ws;    ws += KMAX * sizeof(int);
    int* bucket_ptr  = (int*)ws;    ws += (KMAX + 1) * sizeof(int);
    int* bucket_cur  = (int*)ws;    ws += KMAX * sizeof(int);
    ws = (char*)(((uintptr_t)ws + 15) & ~(uintptr_t)15);   // 16B align for W packs
    half_t* Wf1      = (half_t*)ws; ws += 128 * 128 * sizeof(half_t);
    half_t* Wf2      = (half_t*)ws; ws += 128 * 128 * sizeof(half_t);
    half_t* Wf3      = (half_t*)ws; ws += 128 * 128 * sizeof(half_t);
    // bpack aliases outh (NOT hbuf — GEMM1 writes hbuf while fill still reads bpack).
    // Timeline: scatter writes bpack; csr_count+fill read it; agg1 then overwrites outh.
    int* bpack       = (int*)outh;

    int gC = (E + CHUNK - 1) / CHUNK; // 391
    int gM = (n + 63) / 64;           // 1563 (64-row blocks)
    int gA = (n + 3) / 4;             // 25000

    // 1) bucket_cnt = 0 (stream-ordered before setup's hist atomics)
    hipMemsetAsync(bucket_cnt, 0, KMAX * sizeof(int), stream);
    // 2) setup: W packs + dst histogram
    setup_kernel<<<98 + gC, 256, 0, stream>>>(W1, W2, W3, Wf1, Wf2, Wf3,
                                              dst, bucket_cnt, E);
    // 3) bucket scan
    bucket_scan_kernel<<<1, KMAX, 0, stream>>>(bucket_cnt, bucket_ptr, bucket_cur, K, E);
    // 4) edge partition -> bpack
    bucket_scatter_kernel<<<gC, 256, 0, stream>>>(src, dst, bucket_cur, bpack, E);
    // 5) count+scan -> row_ptr, dis (fill deferred)
    csr_count_kernel<<<K, 256, 0, stream>>>(bpack, bucket_ptr, row_ptr, dis, n, E, K);
    // 6) MERGED: csr fill || GEMM1 (H1 = fp16(dis*(x@W1)))
    fill_gemm_kernel<<<K + gM, 256, 0, stream>>>(bpack, bucket_ptr, row_ptr, csr_src, K,
                                                 x, Wf1, dis, hbuf, n);

    // Layer 1: out1 = relu(agg+b1) fp16
    aggregate_kernel<true><<<gA, 256, 0, stream>>>((const __half2*)hbuf, row_ptr, csr_src, dis, b1, outh, n);
    // Layer 2: H2 = fp16(dis*(out1@W2)) ; out2 = relu(agg+b2) fp16
    gemm_mfma_f16in<<<gM, 256, 0, stream>>>(outh, Wf2, dis, hbuf, n);
    aggregate_kernel<true><<<gA, 256, 0, stream>>>((const __half2*)hbuf, row_ptr, csr_src, dis, b2, outh, n);
    // Layer 3: H3 = fp16(dis*(out2@W3)) ; out = agg+b3 fp32
    gemm_mfma_f16in<<<gM, 256, 0, stream>>>(outh, Wf3, dis, hbuf, n);
    aggregate_kernel<false><<<gA, 256, 0, stream>>>((const __half2*)hbuf, row_ptr, csr_src, dis, b3, out, n);
}